// Round 5
// baseline (1883.484 us; speedup 1.0000x reference)
//
#include <hip/hip_runtime.h>

// Sinkhorn-Knopp, linear domain. R9: PERSISTENT kernel, plain launch only.
//   Key fact: P (4096^2 bf16 = 32 MiB) fits in the register file:
//   32 MiB / 256 CUs = 128 KiB/CU = 64 VGPRs/thread @ 512 thr/CU.
//   k_persist (256 blk x 512 thr, 1 blk/CU, plain <<<>>> launch):
//     phase 0: P = exp((mean+std*eps)/TAU) bf16, packed in 64 VGPRs. P never
//              touches memory (R6 showed 32 MiB P re-read/iter was the floor).
//     iter t:  u_i = rcp(sum_j P_ij v_j) [block-local rows];
//              partial[b][j] = sum_i u_i P_ij  (4 MiB)
//              BAR; block b reduces cols [16b,16b+16) -> csum; BAR
//     final:   out_ij = u_i * P_ij * rcp(csum_j)  (64 MiB write)
//   BAR = hand-rolled grid barrier: bar memset to 0 via hipMemsetAsync (capture
//   -legal, harness reset() itself uses it) before every launch => ABSOLUTE
//   targets k*NBLK, no entry-read race (R8 risk: late block reads stale base
//   => deadlock). Protocol mirrors cooperative-groups grid.sync:
//   release-fence(agent)+relaxed add; RELAXED spin (acquire-per-poll would
//   re-invalidate the XCD L2 from 32 co-located spinners); acquire-fence after.
//   R7/R8 harness failures had no timing block (infra-shaped); coop-launch API
//   and capture queries removed anyway as the only code-side suspects.

constexpr int N    = 4096;
constexpr int IT   = 30;
constexpr int NBLK = 256;           // persistent blocks: exactly 1 per CU
constexpr int ROWS = 16;            // rows per block
constexpr int TPB  = 512;

typedef __attribute__((ext_vector_type(8))) unsigned short ushort8v;

__device__ inline float bf2f(unsigned int h) {
    union { unsigned int u; float f; } x; x.u = h << 16; return x.f;
}
__device__ inline unsigned short f2bf(float f) {
    union { float f; unsigned int u; } x; x.f = f;
    unsigned int r = x.u + 0x7FFFu + ((x.u >> 16) & 1u);   // round-nearest-even
    return (unsigned short)(r >> 16);
}

struct V8 { float v[8]; };
struct V4 { float v[4]; };

__device__ inline V8 unpack8(const ushort8v& s) {
    V8 r;
    #pragma unroll
    for (int k = 0; k < 8; ++k) r.v[k] = bf2f((unsigned int)s[k]);
    return r;
}

// Grid barrier, absolute target (bar pre-zeroed each launch by hipMemsetAsync).
__device__ inline void gbar(unsigned* bar, unsigned target) {
    __syncthreads();                                  // per-wave vmcnt drain
    if (threadIdx.x == 0) {
        __builtin_amdgcn_fence(__ATOMIC_RELEASE, "agent");   // wb this XCD's L2
        __hip_atomic_fetch_add(bar, 1u, __ATOMIC_RELAXED, __HIP_MEMORY_SCOPE_AGENT);
        while (__hip_atomic_load(bar, __ATOMIC_RELAXED,
                                 __HIP_MEMORY_SCOPE_AGENT) < target)
            __builtin_amdgcn_s_sleep(1);
        __builtin_amdgcn_fence(__ATOMIC_ACQUIRE, "agent");   // inv stale lines
    }
    __syncthreads();
}

// ===================== persistent kernel ====================================
__global__ __launch_bounds__(TPB, 2) void k_persist(
        const float* __restrict__ eps, const float* __restrict__ mean,
        const float* __restrict__ stdv, float* __restrict__ out,
        float* __restrict__ partial, float* __restrict__ csum,
        unsigned* __restrict__ bar) {
    __shared__ float ldsRow[ROWS][8];
    __shared__ float ldsU[ROWS];
    __shared__ float red[32][16];
    const int t = threadIdx.x, wv = t >> 6, lane = t & 63;
    const int b = blockIdx.x;
    const int col0 = t * 8;          // this thread's 8 columns
    const int row0 = b * ROWS;       // this block's 16 rows
    unsigned bcnt = 0;

    // ---- phase 0: P in registers, packed bf16 (64 VGPRs) ----
    ushort8v P[ROWS];
    #pragma unroll
    for (int i = 0; i < ROWS; ++i) {
        const size_t rb = (size_t)(row0 + i) * N + col0;
        float4 e0 = *(const float4*)&eps [rb], e1 = *(const float4*)&eps [rb + 4];
        float4 m0 = *(const float4*)&mean[rb], m1 = *(const float4*)&mean[rb + 4];
        float4 s0 = *(const float4*)&stdv[rb], s1 = *(const float4*)&stdv[rb + 4];
        ushort8v o;
        o[0] = f2bf(__expf((m0.x + s0.x * e0.x) * 0.5f));
        o[1] = f2bf(__expf((m0.y + s0.y * e0.y) * 0.5f));
        o[2] = f2bf(__expf((m0.z + s0.z * e0.z) * 0.5f));
        o[3] = f2bf(__expf((m0.w + s0.w * e0.w) * 0.5f));
        o[4] = f2bf(__expf((m1.x + s1.x * e1.x) * 0.5f));
        o[5] = f2bf(__expf((m1.y + s1.y * e1.y) * 0.5f));
        o[6] = f2bf(__expf((m1.z + s1.z * e1.z) * 0.5f));
        o[7] = f2bf(__expf((m1.w + s1.w * e1.w) * 0.5f));
        P[i] = o;
    }

    // ---- iteration 1 compute (v_j == 1) ----
    #pragma unroll
    for (int i = 0; i < ROWS; ++i) {
        V8 pf = unpack8(P[i]);
        float s = pf.v[0] + pf.v[1] + pf.v[2] + pf.v[3]
                + pf.v[4] + pf.v[5] + pf.v[6] + pf.v[7];
        #pragma unroll
        for (int off = 32; off; off >>= 1) s += __shfl_xor(s, off, 64);
        if (lane == 0) ldsRow[i][wv] = s;
    }
    __syncthreads();
    if (t < 8 * ROWS) {                       // 128 threads: 16 rows x 8 waves
        const int row = t >> 3, w = t & 7;
        float s = ldsRow[row][w];
        s += __shfl_xor(s, 1, 64);
        s += __shfl_xor(s, 2, 64);
        s += __shfl_xor(s, 4, 64);
        if (w == 0) ldsU[row] = __builtin_amdgcn_rcpf(s);
    }
    __syncthreads();
    {
        float acc[8] = {0, 0, 0, 0, 0, 0, 0, 0};
        #pragma unroll
        for (int i = 0; i < ROWS; ++i) {
            const float u = ldsU[i];
            V8 pf = unpack8(P[i]);
            #pragma unroll
            for (int k = 0; k < 8; ++k) acc[k] += u * pf.v[k];
        }
        float4 a  = {acc[0], acc[1], acc[2], acc[3]};
        float4 bb = {acc[4], acc[5], acc[6], acc[7]};
        *(float4*)&partial[(size_t)b * N + col0]     = a;
        *(float4*)&partial[(size_t)b * N + col0 + 4] = bb;
    }

    // ---- main loop ----
    for (int it = 1; ; ++it) {
        gbar(bar, (++bcnt) * NBLK);                   // partial ready
        // reduce partial over 256 block-rows for this block's 16 columns
        {
            const int col = row0 + (t & 15);
            const int ch  = t >> 4;                   // 0..31
            const float* pp = partial + (size_t)(ch * 8) * N + col;
            float s = 0.0f;
            #pragma unroll
            for (int r = 0; r < 8; ++r) s += pp[(size_t)r * N];
            red[ch][t & 15] = s;
        }
        __syncthreads();
        if (t < 16) {
            float a = 0.0f;
            #pragma unroll
            for (int c = 0; c < 32; ++c) a += red[c][t];
            csum[row0 + t] = a;
        }
        gbar(bar, (++bcnt) * NBLK);                   // csum ready
        if (it == IT) break;

        // compute phase for iteration it+1
        float4 c0 = *(const float4*)&csum[col0];
        float4 c1 = *(const float4*)&csum[col0 + 4];
        float v[8];
        v[0] = __builtin_amdgcn_rcpf(c0.x);  v[1] = __builtin_amdgcn_rcpf(c0.y);
        v[2] = __builtin_amdgcn_rcpf(c0.z);  v[3] = __builtin_amdgcn_rcpf(c0.w);
        v[4] = __builtin_amdgcn_rcpf(c1.x);  v[5] = __builtin_amdgcn_rcpf(c1.y);
        v[6] = __builtin_amdgcn_rcpf(c1.z);  v[7] = __builtin_amdgcn_rcpf(c1.w);

        #pragma unroll
        for (int i = 0; i < ROWS; ++i) {
            V8 pf = unpack8(P[i]);
            float s = pf.v[0] * v[0] + pf.v[1] * v[1] + pf.v[2] * v[2] + pf.v[3] * v[3]
                    + pf.v[4] * v[4] + pf.v[5] * v[5] + pf.v[6] * v[6] + pf.v[7] * v[7];
            #pragma unroll
            for (int off = 32; off; off >>= 1) s += __shfl_xor(s, off, 64);
            if (lane == 0) ldsRow[i][wv] = s;
        }
        __syncthreads();
        if (t < 8 * ROWS) {
            const int row = t >> 3, w = t & 7;
            float s = ldsRow[row][w];
            s += __shfl_xor(s, 1, 64);
            s += __shfl_xor(s, 2, 64);
            s += __shfl_xor(s, 4, 64);
            if (w == 0) ldsU[row] = __builtin_amdgcn_rcpf(s);
        }
        __syncthreads();
        float acc[8] = {0, 0, 0, 0, 0, 0, 0, 0};
        #pragma unroll
        for (int i = 0; i < ROWS; ++i) {
            const float u = ldsU[i];
            V8 pf = unpack8(P[i]);
            #pragma unroll
            for (int k = 0; k < 8; ++k) acc[k] += u * pf.v[k];
        }
        float4 a  = {acc[0], acc[1], acc[2], acc[3]};
        float4 bb = {acc[4], acc[5], acc[6], acc[7]};
        *(float4*)&partial[(size_t)b * N + col0]     = a;
        *(float4*)&partial[(size_t)b * N + col0 + 4] = bb;
    }

    // ---- final: out_ij = u_i * P_ij * rcp(csum_j) ----
    float4 c0 = *(const float4*)&csum[col0];
    float4 c1 = *(const float4*)&csum[col0 + 4];
    float v[8];
    v[0] = __builtin_amdgcn_rcpf(c0.x);  v[1] = __builtin_amdgcn_rcpf(c0.y);
    v[2] = __builtin_amdgcn_rcpf(c0.z);  v[3] = __builtin_amdgcn_rcpf(c0.w);
    v[4] = __builtin_amdgcn_rcpf(c1.x);  v[5] = __builtin_amdgcn_rcpf(c1.y);
    v[6] = __builtin_amdgcn_rcpf(c1.z);  v[7] = __builtin_amdgcn_rcpf(c1.w);
    #pragma unroll
    for (int i = 0; i < ROWS; ++i) {
        const float u = ldsU[i];
        V8 pf = unpack8(P[i]);
        float4 a  = {pf.v[0] * u * v[0], pf.v[1] * u * v[1],
                     pf.v[2] * u * v[2], pf.v[3] * u * v[3]};
        float4 bb = {pf.v[4] * u * v[4], pf.v[5] * u * v[5],
                     pf.v[6] * u * v[6], pf.v[7] * u * v[7]};
        const size_t rb = (size_t)(row0 + i) * N + col0;
        *(float4*)&out[rb]     = a;
        *(float4*)&out[rb + 4] = bb;
    }
}

// ===================== legacy fallback (ws too small; R6 path, f32) =========
__device__ inline V4 loadP4f(const float* base, size_t e) {
    float4 a = *(const float4*)(base + e);
    V4 r = {{a.x, a.y, a.z, a.w}};
    return r;
}

__global__ __launch_bounds__(TPB) void k_first_f(const float* __restrict__ eps,
                                                 const float* __restrict__ mean,
                                                 const float* __restrict__ stdv,
                                                 float* __restrict__ P,
                                                 float* __restrict__ partial,
                                                 float* __restrict__ u_glob) {
    __shared__ float ldsRow[ROWS][8];
    __shared__ float ldsU[ROWS];
    const int t = threadIdx.x, wv = t >> 6, lane = t & 63;
    const int b = blockIdx.x;
    const int col0 = t * 8, q = t * 4, row0 = b * ROWS;

    V8 raw[ROWS];
    #pragma unroll
    for (int i = 0; i < ROWS; ++i) {
        const size_t rb = (size_t)(row0 + i) * N + col0;
        float4 e0 = *(const float4*)&eps [rb], e1 = *(const float4*)&eps [rb + 4];
        float4 m0 = *(const float4*)&mean[rb], m1 = *(const float4*)&mean[rb + 4];
        float4 s0 = *(const float4*)&stdv[rb], s1 = *(const float4*)&stdv[rb + 4];
        float p[8];
        p[0] = __expf((m0.x + s0.x * e0.x) * 0.5f);
        p[1] = __expf((m0.y + s0.y * e0.y) * 0.5f);
        p[2] = __expf((m0.z + s0.z * e0.z) * 0.5f);
        p[3] = __expf((m0.w + s0.w * e0.w) * 0.5f);
        p[4] = __expf((m1.x + s1.x * e1.x) * 0.5f);
        p[5] = __expf((m1.y + s1.y * e1.y) * 0.5f);
        p[6] = __expf((m1.z + s1.z * e1.z) * 0.5f);
        p[7] = __expf((m1.w + s1.w * e1.w) * 0.5f);
        V8 r = {{p[0], p[1], p[2], p[3], p[4], p[5], p[6], p[7]}};
        raw[i] = r;
        float4 a = {p[0], p[1], p[2], p[3]}, bb = {p[4], p[5], p[6], p[7]};
        *(float4*)(P + rb)     = a;
        *(float4*)(P + rb + 4) = bb;
    }
    #pragma unroll
    for (int i = 0; i < ROWS; ++i) {
        float s = raw[i].v[0] + raw[i].v[1] + raw[i].v[2] + raw[i].v[3]
                + raw[i].v[4] + raw[i].v[5] + raw[i].v[6] + raw[i].v[7];
        #pragma unroll
        for (int off = 32; off; off >>= 1) s += __shfl_xor(s, off, 64);
        if (lane == 0) ldsRow[i][wv] = s;
    }
    __syncthreads();
    if (t < 8 * ROWS) {
        const int row = t >> 3, w = t & 7;
        float s = ldsRow[row][w];
        s += __shfl_xor(s, 1, 64);
        s += __shfl_xor(s, 2, 64);
        s += __shfl_xor(s, 4, 64);
        if (w == 0) {
            float u = __builtin_amdgcn_rcpf(s);
            ldsU[row] = u;
            u_glob[row0 + row] = u;
        }
    }
    __syncthreads();
    float acc[8] = {0, 0, 0, 0, 0, 0, 0, 0};
    #pragma unroll
    for (int i = 0; i < ROWS; ++i) {
        const float u = ldsU[i];
        #pragma unroll
        for (int k = 0; k < 8; ++k) acc[k] += u * raw[i].v[k];
    }
    float4 a  = {acc[0], acc[1], acc[2], acc[3]};
    float4 bb = {acc[4], acc[5], acc[6], acc[7]};
    *(float4*)&partial[(size_t)b * N + q]        = a;
    *(float4*)&partial[(size_t)b * N + 2048 + q] = bb;
}

__global__ __launch_bounds__(TPB) void k_iter_f(const float* __restrict__ P,
                                                const float* __restrict__ csum_prev,
                                                float* __restrict__ partial,
                                                float* __restrict__ u_glob) {
    __shared__ float ldsRow[ROWS][8];
    __shared__ float ldsU[ROWS];
    const int t = threadIdx.x, wv = t >> 6, lane = t & 63;
    const int b = blockIdx.x;
    const int col0 = t * 8, q = t * 4, row0 = b * ROWS;

    float4 c0 = *(const float4*)&csum_prev[q];
    float4 c1 = *(const float4*)&csum_prev[2048 + q];
    float v[8];
    v[0] = __builtin_amdgcn_rcpf(c0.x);  v[1] = __builtin_amdgcn_rcpf(c0.y);
    v[2] = __builtin_amdgcn_rcpf(c0.z);  v[3] = __builtin_amdgcn_rcpf(c0.w);
    v[4] = __builtin_amdgcn_rcpf(c1.x);  v[5] = __builtin_amdgcn_rcpf(c1.y);
    v[6] = __builtin_amdgcn_rcpf(c1.z);  v[7] = __builtin_amdgcn_rcpf(c1.w);

    V8 raw[ROWS];
    #pragma unroll
    for (int i = 0; i < ROWS; ++i) {
        const size_t rb = (size_t)(row0 + i) * N + col0;
        float4 a = *(const float4*)(P + rb);
        float4 bb = *(const float4*)(P + rb + 4);
        V8 r = {{a.x, a.y, a.z, a.w, bb.x, bb.y, bb.z, bb.w}};
        raw[i] = r;
    }
    #pragma unroll
    for (int i = 0; i < ROWS; ++i) {
        float s = raw[i].v[0] * v[0] + raw[i].v[1] * v[1] + raw[i].v[2] * v[2] + raw[i].v[3] * v[3]
                + raw[i].v[4] * v[4] + raw[i].v[5] * v[5] + raw[i].v[6] * v[6] + raw[i].v[7] * v[7];
        #pragma unroll
        for (int off = 32; off; off >>= 1) s += __shfl_xor(s, off, 64);
        if (lane == 0) ldsRow[i][wv] = s;
    }
    __syncthreads();
    if (t < 8 * ROWS) {
        const int row = t >> 3, w = t & 7;
        float s = ldsRow[row][w];
        s += __shfl_xor(s, 1, 64);
        s += __shfl_xor(s, 2, 64);
        s += __shfl_xor(s, 4, 64);
        if (w == 0) {
            float u = __builtin_amdgcn_rcpf(s);
            ldsU[row] = u;
            u_glob[row0 + row] = u;
        }
    }
    __syncthreads();
    float acc[8] = {0, 0, 0, 0, 0, 0, 0, 0};
    #pragma unroll
    for (int i = 0; i < ROWS; ++i) {
        const float u = ldsU[i];
        #pragma unroll
        for (int k = 0; k < 8; ++k) acc[k] += u * raw[i].v[k];
    }
    float4 a  = {acc[0], acc[1], acc[2], acc[3]};
    float4 bb = {acc[4], acc[5], acc[6], acc[7]};
    *(float4*)&partial[(size_t)b * N + q]        = a;
    *(float4*)&partial[(size_t)b * N + 2048 + q] = bb;
}

__global__ __launch_bounds__(512) void k_reduce(const float* __restrict__ partial,
                                                float* __restrict__ csum_cur) {
    __shared__ float red[16][32];
    const int t = threadIdx.x;
    const int lane = t & 63, wv = t >> 6;
    const int c     = blockIdx.x * 32 + (lane & 31);
    const int slice = wv * 2 + (lane >> 5);
    const float* p = partial + (size_t)(slice * 16) * N + c;
    float s = 0.0f;
    #pragma unroll 16
    for (int r = 0; r < 16; ++r)
        s += p[(size_t)r * N];
    red[slice][lane & 31] = s;
    __syncthreads();
    if (t < 32) {
        float acc = 0.0f;
        #pragma unroll
        for (int sl = 0; sl < 16; ++sl) acc += red[sl][t];
        csum_cur[blockIdx.x * 32 + t] = acc;
    }
}

__global__ __launch_bounds__(256) void k_final_f(const float* __restrict__ P,
                                                 const float* __restrict__ u_glob,
                                                 const float* __restrict__ csum_last,
                                                 float* __restrict__ out) {
    const int idx = blockIdx.x * 256 + threadIdx.x;
    const int row = idx >> 10;
    const int c4  = (idx & 1023) * 4;
    const float u = u_glob[row];
    const int perm = ((c4 & 4) ? 2048 : 0) + ((c4 >> 3) << 2);
    float4 cc = *(const float4*)&csum_last[perm];
    V4 p = loadP4f(P, (size_t)row * N + c4);
    float4 r;
    r.x = p.v[0] * u * __builtin_amdgcn_rcpf(cc.x);
    r.y = p.v[1] * u * __builtin_amdgcn_rcpf(cc.y);
    r.z = p.v[2] * u * __builtin_amdgcn_rcpf(cc.z);
    r.w = p.v[3] * u * __builtin_amdgcn_rcpf(cc.w);
    ((float4*)out)[(size_t)idx] = r;
}

// ------------------------------------------------------------- launcher -----
extern "C" void kernel_launch(void* const* d_in, const int* in_sizes, int n_in,
                              void* d_out, int out_size, void* d_ws, size_t ws_size,
                              hipStream_t stream) {
    const float* eps  = (const float*)d_in[0];
    const float* mean = (const float*)d_in[1];
    const float* stdv = (const float*)d_in[2];
    float* out = (float*)d_out;
    char* ws = (char*)d_ws;

    // ws: [csum 16K][bufB 16K][u_glob 16K][bar @48K][partial 4MiB @64K]
    float* bufA   = (float*)ws;
    float* bufB   = bufA + N;
    float* u_glob = bufB + N;
    unsigned* bar = (unsigned*)(ws + 48 * 1024);
    const size_t partOff = 64 * 1024;
    float* partial = (float*)(ws + partOff);
    const size_t partBytes = (size_t)NBLK * N * sizeof(float);     // 4 MiB

    if (ws_size >= partOff + partBytes) {
        float* csum = bufA;
        // Reset barrier counter every invocation (stream-ordered, capture-legal;
        // becomes part of the captured graph => reset on every replay too).
        hipMemsetAsync(bar, 0, sizeof(unsigned), stream);
        k_persist<<<dim3(NBLK), dim3(TPB), 0, stream>>>(
            eps, mean, stdv, out, partial, csum, bar);
        return;
    }

    // legacy f32 fallback (P lives in d_out) — correctness only
    const int finalGrid = N * N / 4 / 256;
    float* cs[2] = { bufA, bufB };
    float* P = out;
    k_first_f<<<NBLK, TPB, 0, stream>>>(eps, mean, stdv, P, partial, u_glob);
    k_reduce<<<128, 512, 0, stream>>>(partial, cs[1]);
    for (int t = 2; t <= IT; ++t) {
        k_iter_f<<<NBLK, TPB, 0, stream>>>(P, cs[(t - 1) & 1], partial, u_glob);
        k_reduce<<<128, 512, 0, stream>>>(partial, cs[t & 1]);
    }
    k_final_f<<<finalGrid, 256, 0, stream>>>(P, u_glob, cs[IT & 1], out);
}

// Round 6
// 1610.613 us; speedup vs baseline: 1.1694x; 1.1694x over previous
//
#include <hip/hip_runtime.h>

// Sinkhorn-Knopp, linear domain. R10: PERSISTENT kernel, FENCELESS barriers.
//   P (4096^2 bf16 = 32 MiB) lives in VGPRs: 64 VGPRs/thread @ 512 thr x 256 blk.
//   R9 post-mortem: grid barrier with agent fences = buffer_wbl2 + buffer_inv
//   (full L2 writeback+invalidate, x32 redundant per XCD, x60 barriers) =>
//   1749us, FETCH 750MB of phantom re-fetch. Fix (MI300-class idiom): exchange
//   partial/csum/bar ONLY via agent-scope RELAXED atomic ld/st (sc0 sc1 flags,
//   bypass L2, LLC-coherent) => no stale L2 copies can exist => barrier needs
//   NO cache maintenance: __syncthreads [drains vmcnt => sc1 stores at LLC]
//   -> relaxed fetch_add -> relaxed spin -> __syncthreads.
//   Structure per iter: compute partial (block owns 16 rows) -> BAR ->
//   block b reduces cols [16b,16b+16) -> csum -> BAR -> next compute.
//   final: out_ij = u_i * P_ij * rcp(csum_j), normal stores (kernel-end fence).

constexpr int N    = 4096;
constexpr int IT   = 30;
constexpr int NBLK = 256;           // persistent blocks: exactly 1 per CU
constexpr int ROWS = 16;            // rows per block
constexpr int TPB  = 512;

typedef __attribute__((ext_vector_type(8))) unsigned short ushort8v;

__device__ inline float bf2f(unsigned int h) {
    union { unsigned int u; float f; } x; x.u = h << 16; return x.f;
}
__device__ inline unsigned short f2bf(float f) {
    union { float f; unsigned int u; } x; x.f = f;
    unsigned int r = x.u + 0x7FFFu + ((x.u >> 16) & 1u);   // round-nearest-even
    return (unsigned short)(r >> 16);
}

struct V8 { float v[8]; };
struct V4 { float v[4]; };

__device__ inline V8 unpack8(const ushort8v& s) {
    V8 r;
    #pragma unroll
    for (int k = 0; k < 8; ++k) r.v[k] = bf2f((unsigned int)s[k]);
    return r;
}

// ---- LLC-coherent (agent-scope, relaxed) accessors: emit sc0/sc1, bypass L2
__device__ inline void st8c(float* p, float a, float b) {
    union { float f[2]; unsigned long long u; } x; x.f[0] = a; x.f[1] = b;
    __hip_atomic_store((unsigned long long*)p, x.u,
                       __ATOMIC_RELAXED, __HIP_MEMORY_SCOPE_AGENT);
}
__device__ inline float2 ld8c(const float* p) {
    unsigned long long u = __hip_atomic_load((const unsigned long long*)p,
                       __ATOMIC_RELAXED, __HIP_MEMORY_SCOPE_AGENT);
    union { unsigned long long u; float f[2]; } x; x.u = u;
    return make_float2(x.f[0], x.f[1]);
}
__device__ inline void st4c(float* p, float v) {
    __hip_atomic_store(p, v, __ATOMIC_RELAXED, __HIP_MEMORY_SCOPE_AGENT);
}

// Grid barrier, NO cache fences. bar pre-zeroed each launch (hipMemsetAsync);
// absolute targets k*NBLK. __syncthreads drains vmcnt(0) => prior sc1 stores
// are at the LLC before the counter increment becomes visible.
__device__ inline void gbar(unsigned* bar, unsigned target) {
    __syncthreads();
    if (threadIdx.x == 0) {
        __hip_atomic_fetch_add(bar, 1u, __ATOMIC_RELAXED, __HIP_MEMORY_SCOPE_AGENT);
        while (__hip_atomic_load(bar, __ATOMIC_RELAXED,
                                 __HIP_MEMORY_SCOPE_AGENT) < target)
            __builtin_amdgcn_s_sleep(2);
    }
    __syncthreads();
}

// ===================== persistent kernel ====================================
__global__ __launch_bounds__(TPB, 2) void k_persist(
        const float* __restrict__ eps, const float* __restrict__ mean,
        const float* __restrict__ stdv, float* __restrict__ out,
        float* __restrict__ partial, float* __restrict__ csum,
        unsigned* __restrict__ bar) {
    __shared__ float  ldsRow[ROWS][8];
    __shared__ float  ldsU[ROWS];
    __shared__ float2 red2[64][8];                 // 4 KB: 64 row-chunks x 8 col-pairs
    const int t = threadIdx.x, wv = t >> 6, lane = t & 63;
    const int b = blockIdx.x;
    const int col0 = t * 8;          // this thread's 8 columns
    const int row0 = b * ROWS;       // this block's 16 rows
    unsigned bcnt = 0;

    // ---- phase 0: P in registers, packed bf16 (64 VGPRs) ----
    ushort8v P[ROWS];
    #pragma unroll
    for (int i = 0; i < ROWS; ++i) {
        const size_t rb = (size_t)(row0 + i) * N + col0;
        float4 e0 = *(const float4*)&eps [rb], e1 = *(const float4*)&eps [rb + 4];
        float4 m0 = *(const float4*)&mean[rb], m1 = *(const float4*)&mean[rb + 4];
        float4 s0 = *(const float4*)&stdv[rb], s1 = *(const float4*)&stdv[rb + 4];
        ushort8v o;
        o[0] = f2bf(__expf((m0.x + s0.x * e0.x) * 0.5f));
        o[1] = f2bf(__expf((m0.y + s0.y * e0.y) * 0.5f));
        o[2] = f2bf(__expf((m0.z + s0.z * e0.z) * 0.5f));
        o[3] = f2bf(__expf((m0.w + s0.w * e0.w) * 0.5f));
        o[4] = f2bf(__expf((m1.x + s1.x * e1.x) * 0.5f));
        o[5] = f2bf(__expf((m1.y + s1.y * e1.y) * 0.5f));
        o[6] = f2bf(__expf((m1.z + s1.z * e1.z) * 0.5f));
        o[7] = f2bf(__expf((m1.w + s1.w * e1.w) * 0.5f));
        P[i] = o;
    }

    // ---- iteration 1 compute (v_j == 1) ----
    #pragma unroll
    for (int i = 0; i < ROWS; ++i) {
        V8 pf = unpack8(P[i]);
        float s = pf.v[0] + pf.v[1] + pf.v[2] + pf.v[3]
                + pf.v[4] + pf.v[5] + pf.v[6] + pf.v[7];
        #pragma unroll
        for (int off = 32; off; off >>= 1) s += __shfl_xor(s, off, 64);
        if (lane == 0) ldsRow[i][wv] = s;
    }
    __syncthreads();
    if (t < 8 * ROWS) {                       // 128 threads: 16 rows x 8 waves
        const int row = t >> 3, w = t & 7;
        float s = ldsRow[row][w];
        s += __shfl_xor(s, 1, 64);
        s += __shfl_xor(s, 2, 64);
        s += __shfl_xor(s, 4, 64);
        if (w == 0) ldsU[row] = __builtin_amdgcn_rcpf(s);
    }
    __syncthreads();
    {
        float acc[8] = {0, 0, 0, 0, 0, 0, 0, 0};
        #pragma unroll
        for (int i = 0; i < ROWS; ++i) {
            const float u = ldsU[i];
            V8 pf = unpack8(P[i]);
            #pragma unroll
            for (int k = 0; k < 8; ++k) acc[k] += u * pf.v[k];
        }
        float* dst = &partial[(size_t)b * N + col0];
        st8c(dst,     acc[0], acc[1]);
        st8c(dst + 2, acc[2], acc[3]);
        st8c(dst + 4, acc[4], acc[5]);
        st8c(dst + 6, acc[6], acc[7]);
    }

    // ---- main loop ----
    for (int it = 1; ; ++it) {
        gbar(bar, (++bcnt) * NBLK);                   // partial ready (at LLC)
        // reduce partial over 256 block-rows for this block's 16 columns
        {
            const int cp = (t & 7) * 2;               // col pair 0,2,..,14
            const int ch = t >> 3;                    // row chunk 0..63 (x4 rows)
            const float* pp = partial + (size_t)(ch * 4) * N + row0 + cp;
            float s0 = 0.0f, s1 = 0.0f;
            #pragma unroll
            for (int r = 0; r < 4; ++r) {
                float2 v2 = ld8c(pp + (size_t)r * N);
                s0 += v2.x; s1 += v2.y;
            }
            red2[ch][t & 7] = make_float2(s0, s1);
        }
        __syncthreads();
        if (t < 16) {
            float a = 0.0f;
            #pragma unroll
            for (int ch = 0; ch < 64; ++ch)
                a += ((const float*)&red2[ch][t >> 1])[t & 1];
            st4c(&csum[row0 + t], a);
        }
        gbar(bar, (++bcnt) * NBLK);                   // csum ready (at LLC)
        if (it == IT) break;

        // compute phase for iteration it+1
        float2 ca = ld8c(&csum[col0]);
        float2 cb = ld8c(&csum[col0 + 2]);
        float2 cc = ld8c(&csum[col0 + 4]);
        float2 cd = ld8c(&csum[col0 + 6]);
        float v[8];
        v[0] = __builtin_amdgcn_rcpf(ca.x);  v[1] = __builtin_amdgcn_rcpf(ca.y);
        v[2] = __builtin_amdgcn_rcpf(cb.x);  v[3] = __builtin_amdgcn_rcpf(cb.y);
        v[4] = __builtin_amdgcn_rcpf(cc.x);  v[5] = __builtin_amdgcn_rcpf(cc.y);
        v[6] = __builtin_amdgcn_rcpf(cd.x);  v[7] = __builtin_amdgcn_rcpf(cd.y);

        #pragma unroll
        for (int i = 0; i < ROWS; ++i) {
            V8 pf = unpack8(P[i]);
            float s = pf.v[0] * v[0] + pf.v[1] * v[1] + pf.v[2] * v[2] + pf.v[3] * v[3]
                    + pf.v[4] * v[4] + pf.v[5] * v[5] + pf.v[6] * v[6] + pf.v[7] * v[7];
            #pragma unroll
            for (int off = 32; off; off >>= 1) s += __shfl_xor(s, off, 64);
            if (lane == 0) ldsRow[i][wv] = s;
        }
        __syncthreads();
        if (t < 8 * ROWS) {
            const int row = t >> 3, w = t & 7;
            float s = ldsRow[row][w];
            s += __shfl_xor(s, 1, 64);
            s += __shfl_xor(s, 2, 64);
            s += __shfl_xor(s, 4, 64);
            if (w == 0) ldsU[row] = __builtin_amdgcn_rcpf(s);
        }
        __syncthreads();
        float acc[8] = {0, 0, 0, 0, 0, 0, 0, 0};
        #pragma unroll
        for (int i = 0; i < ROWS; ++i) {
            const float u = ldsU[i];
            V8 pf = unpack8(P[i]);
            #pragma unroll
            for (int k = 0; k < 8; ++k) acc[k] += u * pf.v[k];
        }
        float* dst = &partial[(size_t)b * N + col0];
        st8c(dst,     acc[0], acc[1]);
        st8c(dst + 2, acc[2], acc[3]);
        st8c(dst + 4, acc[4], acc[5]);
        st8c(dst + 6, acc[6], acc[7]);
    }

    // ---- final: out_ij = u_i * P_ij * rcp(csum_j) ----
    float2 ca = ld8c(&csum[col0]);
    float2 cb = ld8c(&csum[col0 + 2]);
    float2 cc = ld8c(&csum[col0 + 4]);
    float2 cd = ld8c(&csum[col0 + 6]);
    float v[8];
    v[0] = __builtin_amdgcn_rcpf(ca.x);  v[1] = __builtin_amdgcn_rcpf(ca.y);
    v[2] = __builtin_amdgcn_rcpf(cb.x);  v[3] = __builtin_amdgcn_rcpf(cb.y);
    v[4] = __builtin_amdgcn_rcpf(cc.x);  v[5] = __builtin_amdgcn_rcpf(cc.y);
    v[6] = __builtin_amdgcn_rcpf(cd.x);  v[7] = __builtin_amdgcn_rcpf(cd.y);
    #pragma unroll
    for (int i = 0; i < ROWS; ++i) {
        const float u = ldsU[i];
        V8 pf = unpack8(P[i]);
        float4 a  = {pf.v[0] * u * v[0], pf.v[1] * u * v[1],
                     pf.v[2] * u * v[2], pf.v[3] * u * v[3]};
        float4 bb = {pf.v[4] * u * v[4], pf.v[5] * u * v[5],
                     pf.v[6] * u * v[6], pf.v[7] * u * v[7]};
        const size_t rb = (size_t)(row0 + i) * N + col0;
        *(float4*)&out[rb]     = a;
        *(float4*)&out[rb + 4] = bb;
    }
}

// ===================== legacy fallback (ws too small; R6 path, f32) =========
__device__ inline V4 loadP4f(const float* base, size_t e) {
    float4 a = *(const float4*)(base + e);
    V4 r = {{a.x, a.y, a.z, a.w}};
    return r;
}

__global__ __launch_bounds__(TPB) void k_first_f(const float* __restrict__ eps,
                                                 const float* __restrict__ mean,
                                                 const float* __restrict__ stdv,
                                                 float* __restrict__ P,
                                                 float* __restrict__ partial,
                                                 float* __restrict__ u_glob) {
    __shared__ float ldsRow[ROWS][8];
    __shared__ float ldsU[ROWS];
    const int t = threadIdx.x, wv = t >> 6, lane = t & 63;
    const int b = blockIdx.x;
    const int col0 = t * 8, q = t * 4, row0 = b * ROWS;

    V8 raw[ROWS];
    #pragma unroll
    for (int i = 0; i < ROWS; ++i) {
        const size_t rb = (size_t)(row0 + i) * N + col0;
        float4 e0 = *(const float4*)&eps [rb], e1 = *(const float4*)&eps [rb + 4];
        float4 m0 = *(const float4*)&mean[rb], m1 = *(const float4*)&mean[rb + 4];
        float4 s0 = *(const float4*)&stdv[rb], s1 = *(const float4*)&stdv[rb + 4];
        float p[8];
        p[0] = __expf((m0.x + s0.x * e0.x) * 0.5f);
        p[1] = __expf((m0.y + s0.y * e0.y) * 0.5f);
        p[2] = __expf((m0.z + s0.z * e0.z) * 0.5f);
        p[3] = __expf((m0.w + s0.w * e0.w) * 0.5f);
        p[4] = __expf((m1.x + s1.x * e1.x) * 0.5f);
        p[5] = __expf((m1.y + s1.y * e1.y) * 0.5f);
        p[6] = __expf((m1.z + s1.z * e1.z) * 0.5f);
        p[7] = __expf((m1.w + s1.w * e1.w) * 0.5f);
        V8 r = {{p[0], p[1], p[2], p[3], p[4], p[5], p[6], p[7]}};
        raw[i] = r;
        float4 a = {p[0], p[1], p[2], p[3]}, bb = {p[4], p[5], p[6], p[7]};
        *(float4*)(P + rb)     = a;
        *(float4*)(P + rb + 4) = bb;
    }
    #pragma unroll
    for (int i = 0; i < ROWS; ++i) {
        float s = raw[i].v[0] + raw[i].v[1] + raw[i].v[2] + raw[i].v[3]
                + raw[i].v[4] + raw[i].v[5] + raw[i].v[6] + raw[i].v[7];
        #pragma unroll
        for (int off = 32; off; off >>= 1) s += __shfl_xor(s, off, 64);
        if (lane == 0) ldsRow[i][wv] = s;
    }
    __syncthreads();
    if (t < 8 * ROWS) {
        const int row = t >> 3, w = t & 7;
        float s = ldsRow[row][w];
        s += __shfl_xor(s, 1, 64);
        s += __shfl_xor(s, 2, 64);
        s += __shfl_xor(s, 4, 64);
        if (w == 0) {
            float u = __builtin_amdgcn_rcpf(s);
            ldsU[row] = u;
            u_glob[row0 + row] = u;
        }
    }
    __syncthreads();
    float acc[8] = {0, 0, 0, 0, 0, 0, 0, 0};
    #pragma unroll
    for (int i = 0; i < ROWS; ++i) {
        const float u = ldsU[i];
        #pragma unroll
        for (int k = 0; k < 8; ++k) acc[k] += u * raw[i].v[k];
    }
    float4 a  = {acc[0], acc[1], acc[2], acc[3]};
    float4 bb = {acc[4], acc[5], acc[6], acc[7]};
    *(float4*)&partial[(size_t)b * N + q]        = a;
    *(float4*)&partial[(size_t)b * N + 2048 + q] = bb;
}

__global__ __launch_bounds__(TPB) void k_iter_f(const float* __restrict__ P,
                                                const float* __restrict__ csum_prev,
                                                float* __restrict__ partial,
                                                float* __restrict__ u_glob) {
    __shared__ float ldsRow[ROWS][8];
    __shared__ float ldsU[ROWS];
    const int t = threadIdx.x, wv = t >> 6, lane = t & 63;
    const int b = blockIdx.x;
    const int col0 = t * 8, q = t * 4, row0 = b * ROWS;

    float4 c0 = *(const float4*)&csum_prev[q];
    float4 c1 = *(const float4*)&csum_prev[2048 + q];
    float v[8];
    v[0] = __builtin_amdgcn_rcpf(c0.x);  v[1] = __builtin_amdgcn_rcpf(c0.y);
    v[2] = __builtin_amdgcn_rcpf(c0.z);  v[3] = __builtin_amdgcn_rcpf(c0.w);
    v[4] = __builtin_amdgcn_rcpf(c1.x);  v[5] = __builtin_amdgcn_rcpf(c1.y);
    v[6] = __builtin_amdgcn_rcpf(c1.z);  v[7] = __builtin_amdgcn_rcpf(c1.w);

    V8 raw[ROWS];
    #pragma unroll
    for (int i = 0; i < ROWS; ++i) {
        const size_t rb = (size_t)(row0 + i) * N + col0;
        float4 a = *(const float4*)(P + rb);
        float4 bb = *(const float4*)(P + rb + 4);
        V8 r = {{a.x, a.y, a.z, a.w, bb.x, bb.y, bb.z, bb.w}};
        raw[i] = r;
    }
    #pragma unroll
    for (int i = 0; i < ROWS; ++i) {
        float s = raw[i].v[0] * v[0] + raw[i].v[1] * v[1] + raw[i].v[2] * v[2] + raw[i].v[3] * v[3]
                + raw[i].v[4] * v[4] + raw[i].v[5] * v[5] + raw[i].v[6] * v[6] + raw[i].v[7] * v[7];
        #pragma unroll
        for (int off = 32; off; off >>= 1) s += __shfl_xor(s, off, 64);
        if (lane == 0) ldsRow[i][wv] = s;
    }
    __syncthreads();
    if (t < 8 * ROWS) {
        const int row = t >> 3, w = t & 7;
        float s = ldsRow[row][w];
        s += __shfl_xor(s, 1, 64);
        s += __shfl_xor(s, 2, 64);
        s += __shfl_xor(s, 4, 64);
        if (w == 0) {
            float u = __builtin_amdgcn_rcpf(s);
            ldsU[row] = u;
            u_glob[row0 + row] = u;
        }
    }
    __syncthreads();
    float acc[8] = {0, 0, 0, 0, 0, 0, 0, 0};
    #pragma unroll
    for (int i = 0; i < ROWS; ++i) {
        const float u = ldsU[i];
        #pragma unroll
        for (int k = 0; k < 8; ++k) acc[k] += u * raw[i].v[k];
    }
    float4 a  = {acc[0], acc[1], acc[2], acc[3]};
    float4 bb = {acc[4], acc[5], acc[6], acc[7]};
    *(float4*)&partial[(size_t)b * N + q]        = a;
    *(float4*)&partial[(size_t)b * N + 2048 + q] = bb;
}

__global__ __launch_bounds__(512) void k_reduce(const float* __restrict__ partial,
                                                float* __restrict__ csum_cur) {
    __shared__ float red[16][32];
    const int t = threadIdx.x;
    const int lane = t & 63, wv = t >> 6;
    const int c     = blockIdx.x * 32 + (lane & 31);
    const int slice = wv * 2 + (lane >> 5);
    const float* p = partial + (size_t)(slice * 16) * N + c;
    float s = 0.0f;
    #pragma unroll 16
    for (int r = 0; r < 16; ++r)
        s += p[(size_t)r * N];
    red[slice][lane & 31] = s;
    __syncthreads();
    if (t < 32) {
        float acc = 0.0f;
        #pragma unroll
        for (int sl = 0; sl < 16; ++sl) acc += red[sl][t];
        csum_cur[blockIdx.x * 32 + t] = acc;
    }
}

__global__ __launch_bounds__(256) void k_final_f(const float* __restrict__ P,
                                                 const float* __restrict__ u_glob,
                                                 const float* __restrict__ csum_last,
                                                 float* __restrict__ out) {
    const int idx = blockIdx.x * 256 + threadIdx.x;
    const int row = idx >> 10;
    const int c4  = (idx & 1023) * 4;
    const float u = u_glob[row];
    const int perm = ((c4 & 4) ? 2048 : 0) + ((c4 >> 3) << 2);
    float4 cc = *(const float4*)&csum_last[perm];
    V4 p = loadP4f(P, (size_t)row * N + c4);
    float4 r;
    r.x = p.v[0] * u * __builtin_amdgcn_rcpf(cc.x);
    r.y = p.v[1] * u * __builtin_amdgcn_rcpf(cc.y);
    r.z = p.v[2] * u * __builtin_amdgcn_rcpf(cc.z);
    r.w = p.v[3] * u * __builtin_amdgcn_rcpf(cc.w);
    ((float4*)out)[(size_t)idx] = r;
}

// ------------------------------------------------------------- launcher -----
extern "C" void kernel_launch(void* const* d_in, const int* in_sizes, int n_in,
                              void* d_out, int out_size, void* d_ws, size_t ws_size,
                              hipStream_t stream) {
    const float* eps  = (const float*)d_in[0];
    const float* mean = (const float*)d_in[1];
    const float* stdv = (const float*)d_in[2];
    float* out = (float*)d_out;
    char* ws = (char*)d_ws;

    // ws: [csum 16K][bufB 16K][u_glob 16K][bar @48K][partial 4MiB @64K]
    float* bufA   = (float*)ws;
    float* bufB   = bufA + N;
    float* u_glob = bufB + N;
    unsigned* bar = (unsigned*)(ws + 48 * 1024);
    const size_t partOff = 64 * 1024;
    float* partial = (float*)(ws + partOff);
    const size_t partBytes = (size_t)NBLK * N * sizeof(float);     // 4 MiB

    if (ws_size >= partOff + partBytes) {
        float* csum = bufA;
        // Reset barrier counter every invocation (stream-ordered, capture-legal;
        // becomes part of the captured graph => reset on every replay too).
        hipMemsetAsync(bar, 0, sizeof(unsigned), stream);
        k_persist<<<dim3(NBLK), dim3(TPB), 0, stream>>>(
            eps, mean, stdv, out, partial, csum, bar);
        return;
    }

    // legacy f32 fallback (P lives in d_out) — correctness only
    const int finalGrid = N * N / 4 / 256;
    float* cs[2] = { bufA, bufB };
    float* P = out;
    k_first_f<<<NBLK, TPB, 0, stream>>>(eps, mean, stdv, P, partial, u_glob);
    k_reduce<<<128, 512, 0, stream>>>(partial, cs[1]);
    for (int t = 2; t <= IT; ++t) {
        k_iter_f<<<NBLK, TPB, 0, stream>>>(P, cs[(t - 1) & 1], partial, u_glob);
        k_reduce<<<128, 512, 0, stream>>>(partial, cs[t & 1]);
    }
    k_final_f<<<finalGrid, 256, 0, stream>>>(P, u_glob, cs[IT & 1], out);
}

// Round 7
// 820.285 us; speedup vs baseline: 2.2961x; 1.9635x over previous
//
#include <hip/hip_runtime.h>

// Sinkhorn-Knopp, linear domain. R11: PERSISTENT kernel, row+col slices in regs.
//   R10 post-mortem: partial-matrix exchange via 8-B scattered UC ops was the
//   cost (5x granule amplification, ~39 MB/iter counted, ~40 us/iter), not the
//   barrier. Fix: eliminate the partial matrix entirely.
//   Block b holds BOTH: rows [16b,16b+16) of P (64 VGPR bf16) and the column
//   strip cols [16b,16b+16) x all 4096 rows (64 VGPR bf16).
//     u-half: u_i = rcp(P_rows . v)   -> writes 64 B   (u for its 16 rows)
//     v-half: v_j = rcp(P_strip^T . u)-> writes 64 B   (v for its 16 cols)
//   Per half, each thread UC-reads its 32 B of the 16-KB shared vector with
//   WIDE global_load_dwordx4 sc0 sc1 (lane-contiguous, no amplification).
//   Cross-XCD traffic: 2 x 4 MiB broadcast/iter (was ~39 MB/iter effective).
//   Strips built once in phase 0: P rows -> ws row-major (cached stores), ONE
//   release-fence(agent) [R9-proven correct] + barrier, then cold strip reads.
//   Barrier: ATOMIC-FREE 2-level flag scan (flag[b]=seq; 8 group leaders scan
//   32 flags; root scans 8 gdone; all spin on alldone) with monotonic seq and
//   >= checks; s_sleep backoff. No same-address atomic serialization.

constexpr int N    = 4096;
constexpr int IT   = 30;
constexpr int NBLK = 256;           // 1 block per CU
constexpr int ROWS = 16;            // rows per block == cols per strip
constexpr int TPB  = 512;

typedef __attribute__((ext_vector_type(8))) unsigned short ushort8v;
typedef __attribute__((ext_vector_type(4))) float f32x4;

__device__ inline float bf2f(unsigned int h) {
    union { unsigned int u; float f; } x; x.u = h << 16; return x.f;
}
__device__ inline unsigned short f2bf(float f) {
    union { float f; unsigned int u; } x; x.f = f;
    unsigned int r = x.u + 0x7FFFu + ((x.u >> 16) & 1u);   // round-nearest-even
    return (unsigned short)(r >> 16);
}

struct V8 { float v[8]; };
struct V4 { float v[4]; };

__device__ inline V8 unpack8(const ushort8v& s) {
    V8 r;
    #pragma unroll
    for (int k = 0; k < 8; ++k) r.v[k] = bf2f((unsigned int)s[k]);
    return r;
}

// ---- wide LLC-coherent load: 16 B, bypasses L2 (sc0 sc1) -------------------
__device__ inline f32x4 ldx4_uc(const float* p) {
    f32x4 r;
    asm volatile("global_load_dwordx4 %0, %1, off sc0 sc1\n\t"
                 "s_waitcnt vmcnt(0)"
                 : "=&v"(r) : "v"(p) : "memory");
    return r;
}
__device__ inline void st4c(float* p, float v) {
    __hip_atomic_store(p, v, __ATOMIC_RELAXED, __HIP_MEMORY_SCOPE_AGENT);
}
__device__ inline unsigned ldf(const unsigned* p) {
    return __hip_atomic_load(p, __ATOMIC_RELAXED, __HIP_MEMORY_SCOPE_AGENT);
}
__device__ inline void stf(unsigned* p, unsigned v) {
    __hip_atomic_store(p, v, __ATOMIC_RELAXED, __HIP_MEMORY_SCOPE_AGENT);
}

// ---- atomic-free tree barrier. bar layout: flag[256] @0, gdone[8] @256,
// alldone @288 (distinct 128-B lines). memset(0) per launch; seq from 1. -----
__device__ inline void gbar(unsigned* bar, unsigned seq, int b, bool fence) {
    unsigned* flag    = bar;
    unsigned* gdone   = bar + 256;
    unsigned* alldone = bar + 288;
    __syncthreads();                       // all waves' vmem drained (per-wave)
    const int t = threadIdx.x;
    if (t < 64) {
        if (fence && t == 0)
            __builtin_amdgcn_fence(__ATOMIC_RELEASE, "agent");  // wbl2, once
        if (t == 0) stf(&flag[b], seq);
        if ((b & 31) == 0) {               // group leader: scan 32 flags
            const unsigned* f = &flag[b];
            for (;;) {
                unsigned x = ldf(&f[t & 31]);
                if (__all((int)(x - seq) >= 0)) break;
                __builtin_amdgcn_s_sleep(2);
            }
            if (t == 0) stf(&gdone[b >> 5], seq);
        }
        if (b == 0) {                      // root: scan 8 gdone
            for (;;) {
                unsigned x = ldf(&gdone[t & 7]);
                if (__all((int)(x - seq) >= 0)) break;
                __builtin_amdgcn_s_sleep(2);
            }
            if (t == 0) stf(alldone, seq);
        }
        for (;;) {                         // everyone: spin on alldone
            unsigned x = ldf(alldone);
            if ((int)(x - seq) >= 0) break;
            __builtin_amdgcn_s_sleep(8);
        }
    }
    __syncthreads();
}

// ===================== persistent kernel ====================================
__global__ __launch_bounds__(TPB, 2) void k_persist(
        const float* __restrict__ eps, const float* __restrict__ mean,
        const float* __restrict__ stdv, float* __restrict__ out,
        unsigned short* __restrict__ Prow, float* __restrict__ u_vec,
        float* __restrict__ v_vec, unsigned* __restrict__ bar) {
    __shared__ float ldsRow[ROWS][8];
    __shared__ float ldsU[ROWS];
    __shared__ float ldsC[ROWS][8];
    const int t = threadIdx.x, wv = t >> 6, lane = t & 63;
    const int b = blockIdx.x;
    const int col0 = t * 8;          // thread's 8 cols (row-slice work)
    const int row0 = b * ROWS;       // block's 16 rows
    const int cb   = b * ROWS;       // block's 16-col strip base
    unsigned seq = 0;

    // ---- phase 0a: P rows in regs + store row-major to ws ----
    ushort8v P[ROWS];
    #pragma unroll
    for (int i = 0; i < ROWS; ++i) {
        const size_t rb = (size_t)(row0 + i) * N + col0;
        float4 e0 = *(const float4*)&eps [rb], e1 = *(const float4*)&eps [rb + 4];
        float4 m0 = *(const float4*)&mean[rb], m1 = *(const float4*)&mean[rb + 4];
        float4 s0 = *(const float4*)&stdv[rb], s1 = *(const float4*)&stdv[rb + 4];
        ushort8v o;
        o[0] = f2bf(__expf((m0.x + s0.x * e0.x) * 0.5f));
        o[1] = f2bf(__expf((m0.y + s0.y * e0.y) * 0.5f));
        o[2] = f2bf(__expf((m0.z + s0.z * e0.z) * 0.5f));
        o[3] = f2bf(__expf((m0.w + s0.w * e0.w) * 0.5f));
        o[4] = f2bf(__expf((m1.x + s1.x * e1.x) * 0.5f));
        o[5] = f2bf(__expf((m1.y + s1.y * e1.y) * 0.5f));
        o[6] = f2bf(__expf((m1.z + s1.z * e1.z) * 0.5f));
        o[7] = f2bf(__expf((m1.w + s1.w * e1.w) * 0.5f));
        P[i] = o;
        *(ushort8v*)(Prow + rb) = o;               // cached, coalesced
    }

    // ---- B0: fence (push Prow to LLC) + barrier; then read col strip ----
    gbar(bar, ++seq, b, true);
    ushort8v CT[2 * 8];        // CT[2r]=cols j0..7, CT[2r+1]=j8..15, row k=8t+r
    #pragma unroll
    for (int r = 0; r < 8; ++r) {
        const size_t kk = (size_t)(t * 8 + r) * N + cb;   // cold or own lines
        CT[2 * r]     = *(const ushort8v*)(Prow + kk);
        CT[2 * r + 1] = *(const ushort8v*)(Prow + kk + 8);
    }

    // ---- 30 iterations of {u-half, BAR, v-half, BAR} ----
    for (int it = 1; it <= IT; ++it) {
        // u-half: u_i = rcp(sum_j P_ij v_j); v == 1 on first iteration
        float v8[8];
        if (it == 1) {
            #pragma unroll
            for (int k = 0; k < 8; ++k) v8[k] = 1.0f;
        } else {
            f32x4 a = ldx4_uc(v_vec + col0);
            f32x4 c = ldx4_uc(v_vec + col0 + 4);
            v8[0] = a[0]; v8[1] = a[1]; v8[2] = a[2]; v8[3] = a[3];
            v8[4] = c[0]; v8[5] = c[1]; v8[6] = c[2]; v8[7] = c[3];
        }
        #pragma unroll
        for (int i = 0; i < ROWS; ++i) {
            V8 pf = unpack8(P[i]);
            float s = pf.v[0] * v8[0] + pf.v[1] * v8[1] + pf.v[2] * v8[2] + pf.v[3] * v8[3]
                    + pf.v[4] * v8[4] + pf.v[5] * v8[5] + pf.v[6] * v8[6] + pf.v[7] * v8[7];
            #pragma unroll
            for (int off = 32; off; off >>= 1) s += __shfl_xor(s, off, 64);
            if (lane == 0) ldsRow[i][wv] = s;
        }
        __syncthreads();
        if (t < 8 * ROWS) {
            const int row = t >> 3, w = t & 7;
            float s = ldsRow[row][w];
            s += __shfl_xor(s, 1, 64);
            s += __shfl_xor(s, 2, 64);
            s += __shfl_xor(s, 4, 64);
            if (w == 0) {
                float u = __builtin_amdgcn_rcpf(s);
                ldsU[row] = u;                       // final uses last iter's
                st4c(&u_vec[row0 + row], u);
            }
        }
        gbar(bar, ++seq, b, false);                  // u ready

        // v-half: v_j = rcp(sum_k P_kj u_k) over the block's 16-col strip
        f32x4 ua = ldx4_uc(u_vec + col0);
        f32x4 ub = ldx4_uc(u_vec + col0 + 4);
        float uu[8] = {ua[0], ua[1], ua[2], ua[3], ub[0], ub[1], ub[2], ub[3]};
        float acc[16];
        #pragma unroll
        for (int j = 0; j < 16; ++j) acc[j] = 0.0f;
        #pragma unroll
        for (int r = 0; r < 8; ++r) {
            V8 lo = unpack8(CT[2 * r]);
            V8 hi = unpack8(CT[2 * r + 1]);
            const float u = uu[r];
            #pragma unroll
            for (int j = 0; j < 8; ++j) {
                acc[j]     += u * lo.v[j];
                acc[8 + j] += u * hi.v[j];
            }
        }
        #pragma unroll
        for (int off = 32; off; off >>= 1) {
            #pragma unroll
            for (int j = 0; j < 16; ++j) acc[j] += __shfl_xor(acc[j], off, 64);
        }
        if (lane == 0) {
            #pragma unroll
            for (int j = 0; j < 16; ++j) ldsC[j][wv] = acc[j];
        }
        __syncthreads();
        if (t < 8 * ROWS) {
            const int j = t >> 3, w = t & 7;
            float s = ldsC[j][w];
            s += __shfl_xor(s, 1, 64);
            s += __shfl_xor(s, 2, 64);
            s += __shfl_xor(s, 4, 64);
            if (w == 0) st4c(&v_vec[cb + j], __builtin_amdgcn_rcpf(s));
        }
        gbar(bar, ++seq, b, false);                  // v ready
    }

    // ---- final: out_ij = u_i * P_ij * v_j (u in ldsU, v fresh from v_vec) ----
    f32x4 va = ldx4_uc(v_vec + col0);
    f32x4 vb = ldx4_uc(v_vec + col0 + 4);
    float v8[8] = {va[0], va[1], va[2], va[3], vb[0], vb[1], vb[2], vb[3]};
    #pragma unroll
    for (int i = 0; i < ROWS; ++i) {
        const float u = ldsU[i];
        V8 pf = unpack8(P[i]);
        float4 a  = {pf.v[0] * u * v8[0], pf.v[1] * u * v8[1],
                     pf.v[2] * u * v8[2], pf.v[3] * u * v8[3]};
        float4 bb = {pf.v[4] * u * v8[4], pf.v[5] * u * v8[5],
                     pf.v[6] * u * v8[6], pf.v[7] * u * v8[7]};
        const size_t rb = (size_t)(row0 + i) * N + col0;
        *(float4*)&out[rb]     = a;
        *(float4*)&out[rb + 4] = bb;
    }
}

// ===================== legacy fallback (ws too small; multi-launch f32) =====
__device__ inline V4 loadP4f(const float* base, size_t e) {
    float4 a = *(const float4*)(base + e);
    V4 r = {{a.x, a.y, a.z, a.w}};
    return r;
}

__global__ __launch_bounds__(TPB) void k_first_f(const float* __restrict__ eps,
                                                 const float* __restrict__ mean,
                                                 const float* __restrict__ stdv,
                                                 float* __restrict__ P,
                                                 float* __restrict__ partial,
                                                 float* __restrict__ u_glob) {
    __shared__ float ldsRow[ROWS][8];
    __shared__ float ldsU[ROWS];
    const int t = threadIdx.x, wv = t >> 6, lane = t & 63;
    const int b = blockIdx.x;
    const int col0 = t * 8, q = t * 4, row0 = b * ROWS;

    V8 raw[ROWS];
    #pragma unroll
    for (int i = 0; i < ROWS; ++i) {
        const size_t rb = (size_t)(row0 + i) * N + col0;
        float4 e0 = *(const float4*)&eps [rb], e1 = *(const float4*)&eps [rb + 4];
        float4 m0 = *(const float4*)&mean[rb], m1 = *(const float4*)&mean[rb + 4];
        float4 s0 = *(const float4*)&stdv[rb], s1 = *(const float4*)&stdv[rb + 4];
        float p[8];
        p[0] = __expf((m0.x + s0.x * e0.x) * 0.5f);
        p[1] = __expf((m0.y + s0.y * e0.y) * 0.5f);
        p[2] = __expf((m0.z + s0.z * e0.z) * 0.5f);
        p[3] = __expf((m0.w + s0.w * e0.w) * 0.5f);
        p[4] = __expf((m1.x + s1.x * e1.x) * 0.5f);
        p[5] = __expf((m1.y + s1.y * e1.y) * 0.5f);
        p[6] = __expf((m1.z + s1.z * e1.z) * 0.5f);
        p[7] = __expf((m1.w + s1.w * e1.w) * 0.5f);
        V8 r = {{p[0], p[1], p[2], p[3], p[4], p[5], p[6], p[7]}};
        raw[i] = r;
        float4 a = {p[0], p[1], p[2], p[3]}, bb = {p[4], p[5], p[6], p[7]};
        *(float4*)(P + rb)     = a;
        *(float4*)(P + rb + 4) = bb;
    }
    #pragma unroll
    for (int i = 0; i < ROWS; ++i) {
        float s = raw[i].v[0] + raw[i].v[1] + raw[i].v[2] + raw[i].v[3]
                + raw[i].v[4] + raw[i].v[5] + raw[i].v[6] + raw[i].v[7];
        #pragma unroll
        for (int off = 32; off; off >>= 1) s += __shfl_xor(s, off, 64);
        if (lane == 0) ldsRow[i][wv] = s;
    }
    __syncthreads();
    if (t < 8 * ROWS) {
        const int row = t >> 3, w = t & 7;
        float s = ldsRow[row][w];
        s += __shfl_xor(s, 1, 64);
        s += __shfl_xor(s, 2, 64);
        s += __shfl_xor(s, 4, 64);
        if (w == 0) {
            float u = __builtin_amdgcn_rcpf(s);
            ldsU[row] = u;
            u_glob[row0 + row] = u;
        }
    }
    __syncthreads();
    float acc[8] = {0, 0, 0, 0, 0, 0, 0, 0};
    #pragma unroll
    for (int i = 0; i < ROWS; ++i) {
        const float u = ldsU[i];
        #pragma unroll
        for (int k = 0; k < 8; ++k) acc[k] += u * raw[i].v[k];
    }
    float4 a  = {acc[0], acc[1], acc[2], acc[3]};
    float4 bb = {acc[4], acc[5], acc[6], acc[7]};
    *(float4*)&partial[(size_t)b * N + q]        = a;
    *(float4*)&partial[(size_t)b * N + 2048 + q] = bb;
}

__global__ __launch_bounds__(TPB) void k_iter_f(const float* __restrict__ P,
                                                const float* __restrict__ csum_prev,
                                                float* __restrict__ partial,
                                                float* __restrict__ u_glob) {
    __shared__ float ldsRow[ROWS][8];
    __shared__ float ldsU[ROWS];
    const int t = threadIdx.x, wv = t >> 6, lane = t & 63;
    const int b = blockIdx.x;
    const int col0 = t * 8, q = t * 4, row0 = b * ROWS;

    float4 c0 = *(const float4*)&csum_prev[q];
    float4 c1 = *(const float4*)&csum_prev[2048 + q];
    float v[8];
    v[0] = __builtin_amdgcn_rcpf(c0.x);  v[1] = __builtin_amdgcn_rcpf(c0.y);
    v[2] = __builtin_amdgcn_rcpf(c0.z);  v[3] = __builtin_amdgcn_rcpf(c0.w);
    v[4] = __builtin_amdgcn_rcpf(c1.x);  v[5] = __builtin_amdgcn_rcpf(c1.y);
    v[6] = __builtin_amdgcn_rcpf(c1.z);  v[7] = __builtin_amdgcn_rcpf(c1.w);

    V8 raw[ROWS];
    #pragma unroll
    for (int i = 0; i < ROWS; ++i) {
        const size_t rb = (size_t)(row0 + i) * N + col0;
        float4 a = *(const float4*)(P + rb);
        float4 bb = *(const float4*)(P + rb + 4);
        V8 r = {{a.x, a.y, a.z, a.w, bb.x, bb.y, bb.z, bb.w}};
        raw[i] = r;
    }
    #pragma unroll
    for (int i = 0; i < ROWS; ++i) {
        float s = raw[i].v[0] * v[0] + raw[i].v[1] * v[1] + raw[i].v[2] * v[2] + raw[i].v[3] * v[3]
                + raw[i].v[4] * v[4] + raw[i].v[5] * v[5] + raw[i].v[6] * v[6] + raw[i].v[7] * v[7];
        #pragma unroll
        for (int off = 32; off; off >>= 1) s += __shfl_xor(s, off, 64);
        if (lane == 0) ldsRow[i][wv] = s;
    }
    __syncthreads();
    if (t < 8 * ROWS) {
        const int row = t >> 3, w = t & 7;
        float s = ldsRow[row][w];
        s += __shfl_xor(s, 1, 64);
        s += __shfl_xor(s, 2, 64);
        s += __shfl_xor(s, 4, 64);
        if (w == 0) {
            float u = __builtin_amdgcn_rcpf(s);
            ldsU[row] = u;
            u_glob[row0 + row] = u;
        }
    }
    __syncthreads();
    float acc[8] = {0, 0, 0, 0, 0, 0, 0, 0};
    #pragma unroll
    for (int i = 0; i < ROWS; ++i) {
        const float u = ldsU[i];
        #pragma unroll
        for (int k = 0; k < 8; ++k) acc[k] += u * raw[i].v[k];
    }
    float4 a  = {acc[0], acc[1], acc[2], acc[3]};
    float4 bb = {acc[4], acc[5], acc[6], acc[7]};
    *(float4*)&partial[(size_t)b * N + q]        = a;
    *(float4*)&partial[(size_t)b * N + 2048 + q] = bb;
}

__global__ __launch_bounds__(512) void k_reduce(const float* __restrict__ partial,
                                                float* __restrict__ csum_cur) {
    __shared__ float red[16][32];
    const int t = threadIdx.x;
    const int lane = t & 63, wv = t >> 6;
    const int c     = blockIdx.x * 32 + (lane & 31);
    const int slice = wv * 2 + (lane >> 5);
    const float* p = partial + (size_t)(slice * 16) * N + c;
    float s = 0.0f;
    #pragma unroll 16
    for (int r = 0; r < 16; ++r)
        s += p[(size_t)r * N];
    red[slice][lane & 31] = s;
    __syncthreads();
    if (t < 32) {
        float acc = 0.0f;
        #pragma unroll
        for (int sl = 0; sl < 16; ++sl) acc += red[sl][t];
        csum_cur[blockIdx.x * 32 + t] = acc;
    }
}

__global__ __launch_bounds__(256) void k_final_f(const float* __restrict__ P,
                                                 const float* __restrict__ u_glob,
                                                 const float* __restrict__ csum_last,
                                                 float* __restrict__ out) {
    const int idx = blockIdx.x * 256 + threadIdx.x;
    const int row = idx >> 10;
    const int c4  = (idx & 1023) * 4;
    const float u = u_glob[row];
    const int perm = ((c4 & 4) ? 2048 : 0) + ((c4 >> 3) << 2);
    float4 cc = *(const float4*)&csum_last[perm];
    V4 p = loadP4f(P, (size_t)row * N + c4);
    float4 r;
    r.x = p.v[0] * u * __builtin_amdgcn_rcpf(cc.x);
    r.y = p.v[1] * u * __builtin_amdgcn_rcpf(cc.y);
    r.z = p.v[2] * u * __builtin_amdgcn_rcpf(cc.z);
    r.w = p.v[3] * u * __builtin_amdgcn_rcpf(cc.w);
    ((float4*)out)[(size_t)idx] = r;
}

// ------------------------------------------------------------- launcher -----
extern "C" void kernel_launch(void* const* d_in, const int* in_sizes, int n_in,
                              void* d_out, int out_size, void* d_ws, size_t ws_size,
                              hipStream_t stream) {
    const float* eps  = (const float*)d_in[0];
    const float* mean = (const float*)d_in[1];
    const float* stdv = (const float*)d_in[2];
    float* out = (float*)d_out;
    char* ws = (char*)d_ws;

    // ws: [u_vec 16K @0][v_vec 16K @16K][bar 2K @32K][Prow 32MiB @64K]
    float* u_vec = (float*)ws;
    float* v_vec = (float*)(ws + 16 * 1024);
    unsigned* bar = (unsigned*)(ws + 32 * 1024);
    unsigned short* Prow = (unsigned short*)(ws + 64 * 1024);
    const size_t need = 64 * 1024 + (size_t)N * N * sizeof(unsigned short);

    if (ws_size >= need) {
        // Reset barrier flags every invocation (stream-ordered, capture-legal).
        hipMemsetAsync(bar, 0, 2048, stream);
        k_persist<<<dim3(NBLK), dim3(TPB), 0, stream>>>(
            eps, mean, stdv, out, Prow, u_vec, v_vec, bar);
        return;
    }

    // legacy f32 fallback (P lives in d_out) — correctness only
    float* bufA   = (float*)ws;
    float* bufB   = bufA + N;
    float* u_glob = bufB + N;
    const size_t partOff = 64 * 1024;
    float* partial = (float*)(ws + partOff);
    const int finalGrid = N * N / 4 / 256;
    float* cs[2] = { bufA, bufB };
    float* P = out;
    k_first_f<<<NBLK, TPB, 0, stream>>>(eps, mean, stdv, P, partial, u_glob);
    k_reduce<<<128, 512, 0, stream>>>(partial, cs[1]);
    for (int t = 2; t <= IT; ++t) {
        k_iter_f<<<NBLK, TPB, 0, stream>>>(P, cs[(t - 1) & 1], partial, u_glob);
        k_reduce<<<128, 512, 0, stream>>>(partial, cs[t & 1]);
    }
    k_final_f<<<finalGrid, 256, 0, stream>>>(P, u_glob, cs[IT & 1], out);
}